// Round 1
// 306.220 us; speedup vs baseline: 1.0005x; 1.0005x over previous
//
#include <hip/hip_runtime.h>

#define BATCH 32

typedef float f32x4 __attribute__((ext_vector_type(4)));

// Kernel 1: per-row duration scan + inverse-index scatter + totals.
// One block (256 threads) per batch row; each thread owns S/256 consecutive
// source positions. idxmap is only B*T ints (~475 KB) — trivial traffic.
// (Unchanged from the verified 306 µs version.)
__global__ void lr_scan_kernel(const float* __restrict__ dur,
                               const unsigned int* __restrict__ scale_raw,
                               float* __restrict__ out_tail,   // B floats (total_lengths, output 1)
                               int* __restrict__ totals,       // B ints (workspace)
                               int* __restrict__ idxmap,       // B*T ints (workspace)
                               int S, int T) {
    __shared__ int partial[256];
    const int b = blockIdx.x;
    const int tid = threadIdx.x;

    // duration_scale dtype is ambiguous (python scalar). Normal floats have
    // exponent bits set => raw >= 0x00800000; small ints don't.
    unsigned int u = scale_raw[0];
    float scale = (u < 0x00800000u) ? (float)(int)u : __uint_as_float(u);

    const int PER = S / 256;            // 4 for S=1024
    int d[8];                           // supports S up to 2048
    int lsum = 0;
    const int base = tid * PER;
    for (int k = 0; k < PER; ++k) {
        float f = dur[b * S + base + k];
        int di = (int)(f * scale + 0.5f);   // trunc of non-negative == round-half-up
        if (di < 1) di = 1;
        d[k] = di;
        lsum += di;
    }
    partial[tid] = lsum;
    __syncthreads();

    // Hillis-Steele inclusive scan over 256 per-thread sums
    for (int off = 1; off < 256; off <<= 1) {
        int t = (tid >= off) ? partial[tid - off] : 0;
        __syncthreads();
        partial[tid] += t;
        __syncthreads();
    }

    int run = partial[tid] - lsum;      // exclusive prefix = start of this thread's span
    for (int k = 0; k < PER; ++k) {
        int e = run + d[k];
        for (int j = run; j < e; ++j)
            idxmap[b * T + j] = base + k;
        run = e;
    }

    if (tid == 255) {
        int total = partial[255];
        totals[b] = total;
        out_tail[b] = (float)total;     // output dtype for the flat buffer is f32
    }
}

// Kernel 2 (fast path, D/4 == 128): 1D grid + bijective chunked XCD swizzle
// (T1, m204 formula) so a source row's 1-7 duplicate frames are consumed by
// blocks on the SAME XCD L2 (poison fill flushes L3 right before us, so
// cross-XCD re-reads of x go to HBM). Each thread owns NT=4 CONSECUTIVE
// output frames at a fixed lane: idxmap entries preloaded (one cache line,
// MLP) and the x4 value is register-reused when s repeats (3.6x avg dup).
template<int D4SHIFT, int NT>
__global__ __launch_bounds__(256) void lr_fill_swz_kernel(
        const f32x4* __restrict__ x4,
        const int* __restrict__ idxmap,
        const int* __restrict__ totals,
        f32x4* __restrict__ out4,
        int S, int T, int nbx, int nwg) {
    constexpr int GPB = 256 >> D4SHIFT;       // frame-groups per block (2)
    constexpr int FPB = GPB * NT;             // frames per block (8)

    // bijective chunked XCD swizzle: blocks with equal (wg % 8) share an XCD
    // under round-robin dispatch; give each a contiguous chunk of work.
    // nwg = 32 * nbx is always a multiple of 8, but keep the general form.
    const int wg = blockIdx.x;
    const int q = nwg >> 3, r = nwg & 7;
    const int xcd = wg & 7, seq = wg >> 3;
    const int swz = (xcd < r ? xcd * (q + 1) : r * (q + 1) + (xcd - r) * q) + seq;

    const int b  = swz / nbx;
    const int tb = swz - b * nbx;
    const int lane = threadIdx.x & ((1 << D4SHIFT) - 1);
    const int grp  = threadIdx.x >> D4SHIFT;
    const int t0 = tb * FPB + grp * NT;       // first of NT consecutive frames
    const int total = totals[b];

    // Preload the NT source indices (consecutive ints, one cache line).
    // t < total implies t < T, and idxmap is initialized for all t < total.
    int sarr[NT];
#pragma unroll
    for (int k = 0; k < NT; ++k) {
        const int t = t0 + k;
        sarr[k] = (t < total) ? idxmap[b * T + t] : -1;
    }

    const long long xbase = ((long long)b * S) << D4SHIFT;
    const long long obase = (((long long)b * T + t0) << D4SHIFT) + lane;

    int s_prev = -1;
    f32x4 v = (f32x4)(0.f, 0.f, 0.f, 0.f);
#pragma unroll
    for (int k = 0; k < NT; ++k) {
        const int t = t0 + k;
        if (t >= T) break;                    // tail block past batch-max length
        f32x4 w = (f32x4)(0.f, 0.f, 0.f, 0.f);
        if (sarr[k] >= 0) {
            if (sarr[k] != s_prev) {          // register dedup of the 2KB row read
                v = x4[xbase + ((long long)sarr[k] << D4SHIFT) + lane];
                s_prev = sarr[k];
            }
            w = v;
        }
        __builtin_nontemporal_store(w, &out4[obase + ((long long)k << D4SHIFT)]);
    }
}

// Generic fallback (any D): the previous verified per-frame kernel.
__global__ __launch_bounds__(256) void lr_fill_kernel(
        const f32x4* __restrict__ x4,
        const int* __restrict__ idxmap,
        const int* __restrict__ totals,
        f32x4* __restrict__ out4,
        int S, int T, int d4shift) {
    const int b = blockIdx.y;
    const int D4m1 = (1 << d4shift) - 1;
    const int lane = threadIdx.x & D4m1;
    const int fpb = 256 >> d4shift;
    const int t = blockIdx.x * fpb + (threadIdx.x >> d4shift);
    if (t >= T) return;

    f32x4 v = (f32x4)(0.f, 0.f, 0.f, 0.f);
    if (t < totals[b]) {
        const int s = idxmap[b * T + t];
        v = x4[(((long long)(b * S + s)) << d4shift) + lane];
    }
    __builtin_nontemporal_store(v, &out4[(((long long)(b * T + t)) << d4shift) + lane]);
}

extern "C" void kernel_launch(void* const* d_in, const int* in_sizes, int n_in,
                              void* d_out, int out_size, void* d_ws, size_t ws_size,
                              hipStream_t stream) {
    const float* x = (const float*)d_in[0];
    const float* dur = (const float*)d_in[1];
    const unsigned int* scale = (const unsigned int*)d_in[2];

    const int B = BATCH;
    const int D = in_sizes[0] / in_sizes[1];   // 512
    const int S = in_sizes[1] / B;             // 1024
    const int T = (out_size - B) / (B * D);    // batch-max total length

    float* out = (float*)d_out;
    float* out_tail = out + (long long)B * T * D;

    int* idxmap = (int*)d_ws;                  // B*T ints
    int* totals = idxmap + (long long)B * T;   // B ints

    lr_scan_kernel<<<B, 256, 0, stream>>>(dur, scale, out_tail, totals, idxmap, S, T);

    const int D4 = D / 4;                      // 128 for D=512
    if (D4 == 128) {
        constexpr int NT = 4;                  // consecutive frames per thread
        const int FPB = (256 >> 7) * NT;       // 8 frames per block
        const int nbx = (T + FPB - 1) / FPB;
        const int nwg = B * nbx;
        lr_fill_swz_kernel<7, NT><<<nwg, 256, 0, stream>>>(
            (const f32x4*)x, idxmap, totals, (f32x4*)out, S, T, nbx, nwg);
    } else {
        int d4shift = 0;
        while ((1 << d4shift) < D4) ++d4shift;
        const int fpb = 256 >> d4shift;
        dim3 grid((T + fpb - 1) / fpb, B);
        lr_fill_kernel<<<grid, 256, 0, stream>>>((const f32x4*)x, idxmap, totals,
                                                 (f32x4*)out, S, T, d4shift);
    }
}